// Round 6
// baseline (674.407 us; speedup 1.0000x reference)
//
#include <hip/hip_runtime.h>
#include <hip/hip_cooperative_groups.h>
#include <math.h>

namespace cg = cooperative_groups;

#define N_NODES 10000
#define N_EDGES 320000
#define F_IN 512
#define HID 256
#define PAD_DEG 80   // max in-degree ~60 (Poisson(32) over 10k nodes); 80 is +8.5 sigma
#define LDSTR 40     // LDS row stride in halves (32 + 8 pad, keeps 16B alignment)
#define N_TILES (157 * 4)   // 157 row-tiles x 4 col-tiles of 64x64

typedef _Float16 half8 __attribute__((ext_vector_type(8)));
typedef float floatx4 __attribute__((ext_vector_type(4)));

__device__ __forceinline__ void fma4(float4& acc, float s, const float4& v) {
    acc.x += s * v.x; acc.y += s * v.y; acc.z += s * v.z; acc.w += s * v.w;
}

// ================= shared device phases =================

__device__ __forceinline__ void phase_build(int gtid, int gsz, const int* __restrict__ ei,
                                            int* __restrict__ count, int* __restrict__ csr) {
    for (int e = gtid; e < N_EDGES; e += gsz) {
        int src = ei[e];
        int dst = ei[N_EDGES + e];
        int pos = atomicAdd(&count[dst], 1);   // final value = in-degree
        csr[dst * PAD_DEG + pos] = src;
    }
}

__device__ __forceinline__ void phase_prep(int gtid, int gsz, const float* __restrict__ W1,
                                           _Float16* __restrict__ Bt_hi, _Float16* __restrict__ Bt_lo,
                                           const int* __restrict__ csr, const int* __restrict__ count,
                                           float* __restrict__ wcsr) {
    for (int idx = gtid; idx < N_NODES * PAD_DEG; idx += gsz) {
        if (idx < F_IN * HID) {                // W1 [512][256] -> [256][512] hi/lo split
            int k = idx >> 8, n = idx & 255;
            float v = W1[idx];
            _Float16 hi = (_Float16)v;
            _Float16 lo = (_Float16)(v - (float)hi);
            Bt_hi[n * F_IN + k] = hi;
            Bt_lo[n * F_IN + k] = lo;
        }
        int n = idx / PAD_DEG, j = idx - n * PAD_DEG;
        int deg = count[n];
        if (j < deg) {
            int s = csr[idx];
            int cs = count[s];
            wcsr[idx] = rsqrtf((float)((cs > 0 ? cs : 1) * deg));
        }
    }
}

__device__ __forceinline__ void phase_gemm(int tid, int t0, int tstride,
        _Float16* As_hi, _Float16* As_lo, _Float16* Bs_hi, _Float16* Bs_lo,
        const float* __restrict__ feature, const _Float16* __restrict__ Bt_hi,
        const _Float16* __restrict__ Bt_lo, const float* __restrict__ b1,
        float* __restrict__ h0) {
    const int lane = tid & 63, w = tid >> 6;
    const int wm = (w >> 1) * 32, wn = (w & 1) * 32;
    const int quad = lane >> 4, l15 = lane & 15;
    const int r = tid >> 2, c = (tid & 3) << 3;
    for (int t = t0; t < N_TILES; t += tstride) {
        int row0 = (t >> 2) * 64, col0 = (t & 3) * 64;
        floatx4 acc[2][2] = {};
        for (int k0 = 0; k0 < F_IN; k0 += 32) {
            float av[8];
            int arow = row0 + r;
            if (arow < N_NODES) {
                float4 v0 = *(const float4*)(feature + (size_t)arow * F_IN + k0 + c);
                float4 v1 = *(const float4*)(feature + (size_t)arow * F_IN + k0 + c + 4);
                av[0] = v0.x; av[1] = v0.y; av[2] = v0.z; av[3] = v0.w;
                av[4] = v1.x; av[5] = v1.y; av[6] = v1.z; av[7] = v1.w;
            } else {
                #pragma unroll
                for (int i = 0; i < 8; ++i) av[i] = 0.f;
            }
            half8 hhi, hlo;
            #pragma unroll
            for (int i = 0; i < 8; ++i) {
                _Float16 h = (_Float16)av[i];
                hhi[i] = h;
                hlo[i] = (_Float16)(av[i] - (float)h);
            }
            *(half8*)&As_hi[r * LDSTR + c] = hhi;
            *(half8*)&As_lo[r * LDSTR + c] = hlo;
            *(half8*)&Bs_hi[r * LDSTR + c] = *(const half8*)(Bt_hi + (size_t)(col0 + r) * F_IN + k0 + c);
            *(half8*)&Bs_lo[r * LDSTR + c] = *(const half8*)(Bt_lo + (size_t)(col0 + r) * F_IN + k0 + c);
            __syncthreads();
            half8 a_hi[2], a_lo[2], b_hi[2], b_lo[2];
            #pragma unroll
            for (int mi = 0; mi < 2; ++mi) {
                int mr = wm + mi * 16 + l15;
                a_hi[mi] = *(half8*)&As_hi[mr * LDSTR + quad * 8];
                a_lo[mi] = *(half8*)&As_lo[mr * LDSTR + quad * 8];
            }
            #pragma unroll
            for (int ni = 0; ni < 2; ++ni) {
                int nr = wn + ni * 16 + l15;
                b_hi[ni] = *(half8*)&Bs_hi[nr * LDSTR + quad * 8];
                b_lo[ni] = *(half8*)&Bs_lo[nr * LDSTR + quad * 8];
            }
            #pragma unroll
            for (int mi = 0; mi < 2; ++mi)
                #pragma unroll
                for (int ni = 0; ni < 2; ++ni) {
                    acc[mi][ni] = __builtin_amdgcn_mfma_f32_16x16x32_f16(a_hi[mi], b_hi[ni], acc[mi][ni], 0, 0, 0);
                    acc[mi][ni] = __builtin_amdgcn_mfma_f32_16x16x32_f16(a_hi[mi], b_lo[ni], acc[mi][ni], 0, 0, 0);
                    acc[mi][ni] = __builtin_amdgcn_mfma_f32_16x16x32_f16(a_lo[mi], b_hi[ni], acc[mi][ni], 0, 0, 0);
                }
            __syncthreads();
        }
        #pragma unroll
        for (int mi = 0; mi < 2; ++mi)
            #pragma unroll
            for (int ni = 0; ni < 2; ++ni) {
                int colb = col0 + wn + ni * 16 + l15;
                float bias = b1[colb];
                #pragma unroll
                for (int reg = 0; reg < 4; ++reg) {
                    int rowb = row0 + wm + mi * 16 + quad * 4 + reg;
                    if (rowb < N_NODES) h0[(size_t)rowb * HID + colb] = acc[mi][ni][reg] + bias;
                }
            }
    }
}

__device__ __forceinline__ void phase_agg1(int n0, int nstride, int lane,
        const float* __restrict__ h0, const int* __restrict__ csr,
        const float* __restrict__ wcsr, const int* __restrict__ count,
        const float* __restrict__ W2, const float* __restrict__ b2,
        float* __restrict__ u0) {
    const int off = lane << 2;
    for (int n = n0; n < N_NODES; n += nstride) {
        int deg = count[n];
        const int*   row  = csr  + (size_t)n * PAD_DEG;
        const float* wrow = wcsr + (size_t)n * PAD_DEG;
        float4 acc0 = {0,0,0,0}, acc1 = {0,0,0,0}, acc2 = {0,0,0,0}, acc3 = {0,0,0,0};
        int j = 0;
        for (; j + 8 <= deg; j += 8) {
            int s0 = row[j+0], s1 = row[j+1], s2 = row[j+2], s3 = row[j+3];
            int s4 = row[j+4], s5 = row[j+5], s6 = row[j+6], s7 = row[j+7];
            float w0 = wrow[j+0], w1 = wrow[j+1], w2 = wrow[j+2], w3 = wrow[j+3];
            float w4 = wrow[j+4], w5 = wrow[j+5], w6 = wrow[j+6], w7 = wrow[j+7];
            float4 v0 = *(const float4*)(h0 + (size_t)s0 * HID + off);
            float4 v1 = *(const float4*)(h0 + (size_t)s1 * HID + off);
            float4 v2 = *(const float4*)(h0 + (size_t)s2 * HID + off);
            float4 v3 = *(const float4*)(h0 + (size_t)s3 * HID + off);
            float4 v4 = *(const float4*)(h0 + (size_t)s4 * HID + off);
            float4 v5 = *(const float4*)(h0 + (size_t)s5 * HID + off);
            float4 v6 = *(const float4*)(h0 + (size_t)s6 * HID + off);
            float4 v7 = *(const float4*)(h0 + (size_t)s7 * HID + off);
            fma4(acc0, w0, v0); fma4(acc1, w1, v1); fma4(acc2, w2, v2); fma4(acc3, w3, v3);
            fma4(acc0, w4, v4); fma4(acc1, w5, v5); fma4(acc2, w6, v6); fma4(acc3, w7, v7);
        }
        for (; j < deg; ++j) {
            float4 v = *(const float4*)(h0 + (size_t)row[j] * HID + off);
            fma4(acc0, wrow[j], v);
        }
        acc0.x += acc1.x + acc2.x + acc3.x;
        acc0.y += acc1.y + acc2.y + acc3.y;
        acc0.z += acc1.z + acc2.z + acc3.z;
        acc0.w += acc1.w + acc2.w + acc3.w;
        acc0.x = fmaxf(acc0.x, 0.f); acc0.y = fmaxf(acc0.y, 0.f);
        acc0.z = fmaxf(acc0.z, 0.f); acc0.w = fmaxf(acc0.w, 0.f);
        float4 wa = *(const float4*)(W2 + (lane << 3));
        float4 wb = *(const float4*)(W2 + (lane << 3) + 4);
        float p0 = acc0.x * wa.x + acc0.y * wa.z + acc0.z * wb.x + acc0.w * wb.z;
        float p1 = acc0.x * wa.y + acc0.y * wa.w + acc0.z * wb.y + acc0.w * wb.w;
        #pragma unroll
        for (int o = 32; o > 0; o >>= 1) {
            p0 += __shfl_down(p0, o);
            p1 += __shfl_down(p1, o);
        }
        if (lane == 0) {
            u0[2 * n]     = p0 + b2[0];
            u0[2 * n + 1] = p1 + b2[1];
        }
    }
}

__device__ __forceinline__ void phase_agg2(int n0, int nstride, int lane,
        const float* __restrict__ u0, const int* __restrict__ csr,
        const float* __restrict__ wcsr, const int* __restrict__ count,
        const float* __restrict__ scale, float* __restrict__ out) {
    for (int n = n0; n < N_NODES; n += nstride) {
        int deg = count[n];
        const int*   row  = csr  + (size_t)n * PAD_DEG;
        const float* wrow = wcsr + (size_t)n * PAD_DEG;
        float a0 = 0.f, a1 = 0.f;
        for (int j = lane; j < deg; j += 64) {
            float wq = wrow[j];
            float2 uv = *(const float2*)(u0 + 2 * (size_t)row[j]);
            a0 += wq * uv.x;
            a1 += wq * uv.y;
        }
        #pragma unroll
        for (int o = 32; o > 0; o >>= 1) {
            a0 += __shfl_down(a0, o);
            a1 += __shfl_down(a1, o);
        }
        if (lane == 0) {
            float un = fmaxf(sqrtf(a0 * a0 + a1 * a1), 1e-15f);
            float t = tanhf(0.5f * un) / un;   // sinh/(1+cosh)==tanh(x/2), overflow-proof
            float p0 = a0 * t, p1 = a1 * t;
            float pn = fmaxf(sqrtf(p0 * p0 + p1 * p1), 1e-12f);
            float s = fminf(fmaxf(scale[0], 0.666f), 0.999f);
            p0 = p0 / pn * s; p1 = p1 / pn * s;
            float nn = fmaxf(sqrtf(p0 * p0 + p1 * p1), 1e-15f);
            if (nn > 1.0f) { p0 = p0 / nn; p1 = p1 / nn; }  // (1-1e-15)==1.0f in fp32
            out[2 * n]     = p0;
            out[2 * n + 1] = p1;
        }
    }
}

// ================= cooperative mega-kernel =================

__global__ __launch_bounds__(256, 4) void k_fused(
        const float* __restrict__ feature, const int* __restrict__ ei,
        const float* __restrict__ W1, const float* __restrict__ b1,
        const float* __restrict__ W2, const float* __restrict__ b2,
        const float* __restrict__ scale, float* __restrict__ out,
        int* __restrict__ count, int* __restrict__ csr, float* __restrict__ wcsr,
        float* __restrict__ h0, float* __restrict__ u0,
        _Float16* __restrict__ Bt_hi, _Float16* __restrict__ Bt_lo) {
    cg::grid_group grid = cg::this_grid();
    __shared__ _Float16 As_hi[64 * LDSTR], As_lo[64 * LDSTR];
    __shared__ _Float16 Bs_hi[64 * LDSTR], Bs_lo[64 * LDSTR];
    const int tid  = threadIdx.x;
    const int gtid = blockIdx.x * 256 + tid;
    const int gsz  = gridDim.x * 256;
    const int lane = tid & 63;
    const int wid0 = blockIdx.x * 4 + (tid >> 6);
    const int wstride = gridDim.x * 4;

    for (int i = gtid; i < 10240; i += gsz) count[i] = 0;   // P0: zero degree counters
    __threadfence();
    grid.sync();
    phase_build(gtid, gsz, ei, count, csr);                 // P1: padded CSR
    __threadfence();
    grid.sync();
    phase_prep(gtid, gsz, W1, Bt_hi, Bt_lo, csr, count, wcsr);  // P2: W1 split + edge wgts
    __threadfence();
    grid.sync();
    phase_gemm(tid, blockIdx.x, gridDim.x, As_hi, As_lo, Bs_hi, Bs_lo,
               feature, Bt_hi, Bt_lo, b1, h0);              // P3: MFMA GEMM
    __threadfence();
    grid.sync();
    phase_agg1(wid0, wstride, lane, h0, csr, wcsr, count, W2, b2, u0);  // P4
    __threadfence();
    grid.sync();
    phase_agg2(wid0, wstride, lane, u0, csr, wcsr, count, scale, out);  // P5
}

// ================= fallback multi-kernel path =================

__global__ void k_build(const int* __restrict__ ei, int* __restrict__ count,
                        int* __restrict__ csr) {
    phase_build(blockIdx.x * blockDim.x + threadIdx.x, gridDim.x * blockDim.x, ei, count, csr);
}

__global__ void k_prep(const float* __restrict__ W1, _Float16* __restrict__ Bt_hi,
                       _Float16* __restrict__ Bt_lo, const int* __restrict__ csr,
                       const int* __restrict__ count, float* __restrict__ wcsr) {
    phase_prep(blockIdx.x * blockDim.x + threadIdx.x, gridDim.x * blockDim.x,
               W1, Bt_hi, Bt_lo, csr, count, wcsr);
}

__global__ __launch_bounds__(256) void k_gemm(const float* __restrict__ feature,
                                              const _Float16* __restrict__ Bt_hi,
                                              const _Float16* __restrict__ Bt_lo,
                                              const float* __restrict__ b1,
                                              float* __restrict__ h0) {
    __shared__ _Float16 As_hi[64 * LDSTR], As_lo[64 * LDSTR];
    __shared__ _Float16 Bs_hi[64 * LDSTR], Bs_lo[64 * LDSTR];
    phase_gemm(threadIdx.x, blockIdx.x, gridDim.x, As_hi, As_lo, Bs_hi, Bs_lo,
               feature, Bt_hi, Bt_lo, b1, h0);
}

__global__ __launch_bounds__(256) void k_agg1(const float* __restrict__ h0,
                                              const int* __restrict__ csr,
                                              const float* __restrict__ wcsr,
                                              const int* __restrict__ count,
                                              const float* __restrict__ W2,
                                              const float* __restrict__ b2,
                                              float* __restrict__ u0) {
    phase_agg1(blockIdx.x * 4 + (threadIdx.x >> 6), gridDim.x * 4, threadIdx.x & 63,
               h0, csr, wcsr, count, W2, b2, u0);
}

__global__ __launch_bounds__(256) void k_agg2(const float* __restrict__ u0,
                                              const int* __restrict__ csr,
                                              const float* __restrict__ wcsr,
                                              const int* __restrict__ count,
                                              const float* __restrict__ scale,
                                              float* __restrict__ out) {
    phase_agg2(blockIdx.x * 4 + (threadIdx.x >> 6), gridDim.x * 4, threadIdx.x & 63,
               u0, csr, wcsr, count, scale, out);
}

// ================= launch =================

extern "C" void kernel_launch(void* const* d_in, const int* in_sizes, int n_in,
                              void* d_out, int out_size, void* d_ws, size_t ws_size,
                              hipStream_t stream) {
    const float* feature = (const float*)d_in[0];
    const int*   ei      = (const int*)d_in[1];
    const float* W1      = (const float*)d_in[2];
    const float* b1      = (const float*)d_in[3];
    const float* W2      = (const float*)d_in[4];
    const float* b2      = (const float*)d_in[5];
    const float* scale   = (const float*)d_in[6];
    float* out = (float*)d_out;

    char* W = (char*)d_ws;
    int*      count = (int*)W;                    // 10240 ints
    int*      csr   = (int*)(W + 40960);          // 800000 ints
    float*    wcsr  = (float*)(W + 3240960);      // 800000 floats
    float*    h0    = (float*)(W + 6440960);      // 2.56M floats
    float*    u0    = (float*)(W + 16680960);     // 20000 floats
    _Float16* Bt_hi = (_Float16*)(W + 16760960);  // 131072 halves
    _Float16* Bt_lo = (_Float16*)(W + 17023104);  // 131072 halves  (~17.3 MB total)

    // size the cooperative grid from the runtime's own occupancy answer
    int blocksPerCU = 0;
    hipError_t qe = hipOccupancyMaxActiveBlocksPerMultiprocessor(
                        &blocksPerCU, (const void*)k_fused, 256, 0);
    int gridBlks = (qe == hipSuccess && blocksPerCU > 0) ? blocksPerCU * 256 : 256;
    if (gridBlks > 1024) gridBlks = 1024;

    void* args[] = {(void*)&feature, (void*)&ei, (void*)&W1, (void*)&b1,
                    (void*)&W2, (void*)&b2, (void*)&scale, (void*)&out,
                    (void*)&count, (void*)&csr, (void*)&wcsr,
                    (void*)&h0, (void*)&u0, (void*)&Bt_hi, (void*)&Bt_lo};
    hipError_t le = hipLaunchCooperativeKernel((const void*)k_fused, dim3(gridBlks),
                                               dim3(256), args, 0, stream);
    if (le != hipSuccess) {
        // deterministic fallback: the round-4 five-dispatch pipeline
        (void)hipMemsetAsync(count, 0, 10240 * sizeof(int), stream);
        k_build<<<dim3((N_EDGES + 255) / 256), dim3(256), 0, stream>>>(ei, count, csr);
        k_prep<<<dim3((N_NODES * PAD_DEG + 255) / 256), dim3(256), 0, stream>>>(W1, Bt_hi, Bt_lo, csr, count, wcsr);
        k_gemm<<<dim3(N_TILES), dim3(256), 0, stream>>>(feature, Bt_hi, Bt_lo, b1, h0);
        k_agg1<<<dim3((N_NODES + 3) / 4), dim3(256), 0, stream>>>(h0, csr, wcsr, count, W2, b2, u0);
        k_agg2<<<dim3((N_NODES + 3) / 4), dim3(256), 0, stream>>>(u0, csr, wcsr, count, scale, out);
    }
}

// Round 7
// 168.647 us; speedup vs baseline: 3.9989x; 3.9989x over previous
//
#include <hip/hip_runtime.h>
#include <math.h>

#define N_NODES 10000
#define N_EDGES 320000
#define F_IN 512
#define HID 256
#define PAD_DEG 80    // max in-degree ~60 (Poisson(32) over 10k nodes); 80 is +8.5 sigma
#define LDSTR 40      // LDS row stride in halves (32 + 8 pad, keeps 16B alignment)
#define N_TILES (157 * 4)     // 157 row-tiles x 4 col-tiles of 64x64
#define A_ROWS 10048          // feature rows padded to tile multiple (rows >=10000 zeroed)
#define A_CHUNKS (A_ROWS * F_IN / 8)   // 643072 8-elem chunks

typedef _Float16 half8 __attribute__((ext_vector_type(8)));
typedef float floatx4 __attribute__((ext_vector_type(4)));

__device__ __forceinline__ void fma4(float4& acc, float s, const float4& v) {
    acc.x += s * v.x; acc.y += s * v.y; acc.z += s * v.z; acc.w += s * v.w;
}

// ---- k_build: CSR histogram+fill  +  A fp16 hi/lo split  +  W1 split/transpose ----
// (A-split and W1-split are count-independent; they fill the latency shadows of the
//  atomic-heavy edge pass. grid = 2512 blocks x 256 = 643072 threads.)

__global__ void k_build(const int* __restrict__ ei, const float* __restrict__ feature,
                        const float* __restrict__ W1, int* __restrict__ count,
                        int* __restrict__ csr, _Float16* __restrict__ A_hi,
                        _Float16* __restrict__ A_lo, _Float16* __restrict__ Bt_hi,
                        _Float16* __restrict__ Bt_lo) {
    int i = blockIdx.x * blockDim.x + threadIdx.x;
    if (i < A_CHUNKS) {                       // split feature [10000][512] -> hi/lo fp16
        int row = i >> 6;                     // 64 chunks per row
        half8 hhi, hlo;
        if (row < N_NODES) {
            const float* src = feature + (size_t)i * 8;
            float4 v0 = *(const float4*)src;
            float4 v1 = *(const float4*)(src + 4);
            float av[8] = {v0.x, v0.y, v0.z, v0.w, v1.x, v1.y, v1.z, v1.w};
            #pragma unroll
            for (int t = 0; t < 8; ++t) {
                _Float16 h = (_Float16)av[t];
                hhi[t] = h;
                hlo[t] = (_Float16)(av[t] - (float)h);
            }
        } else {
            #pragma unroll
            for (int t = 0; t < 8; ++t) { hhi[t] = (_Float16)0.f; hlo[t] = (_Float16)0.f; }
        }
        *(half8*)(A_hi + (size_t)i * 8) = hhi;
        *(half8*)(A_lo + (size_t)i * 8) = hlo;
    }
    if (i < F_IN * HID) {                     // W1 [512][256] -> [256][512] hi/lo split
        int k = i >> 8, n = i & 255;
        float v = W1[i];
        _Float16 hi = (_Float16)v;
        Bt_hi[n * F_IN + k] = hi;
        Bt_lo[n * F_IN + k] = (_Float16)(v - (float)hi);
    }
    if (i < N_EDGES) {                        // padded-CSR build
        int src = ei[i];
        int dst = ei[N_EDGES + i];
        int pos = atomicAdd(&count[dst], 1);  // final value = in-degree
        csr[dst * PAD_DEG + pos] = src;
    }
}

// ---- k_prep: per-edge symmetric-norm weights (needs completed counts) ----

__global__ void k_prep(const int* __restrict__ csr, const int* __restrict__ count,
                       float* __restrict__ wcsr) {
    int idx = blockIdx.x * blockDim.x + threadIdx.x;
    if (idx >= N_NODES * PAD_DEG) return;
    int n = idx / PAD_DEG, j = idx - n * PAD_DEG;
    int deg = count[n];
    if (j < deg) {
        int s = csr[idx];
        int cs = count[s];
        wcsr[idx] = rsqrtf((float)((cs > 0 ? cs : 1) * deg));
    }
}

// ---- k_gemm: h0 = feature @ W1 + b1 via 3-term fp16-split MFMA (all inputs pre-split) ----

__global__ __launch_bounds__(256) void k_gemm(const _Float16* __restrict__ A_hi,
                                              const _Float16* __restrict__ A_lo,
                                              const _Float16* __restrict__ Bt_hi,
                                              const _Float16* __restrict__ Bt_lo,
                                              const float* __restrict__ b1,
                                              float* __restrict__ h0) {
    __shared__ _Float16 As_hi[64 * LDSTR], As_lo[64 * LDSTR];
    __shared__ _Float16 Bs_hi[64 * LDSTR], Bs_lo[64 * LDSTR];
    const int tid = threadIdx.x;
    const int lane = tid & 63, w = tid >> 6;
    const int wm = (w >> 1) * 32, wn = (w & 1) * 32;
    const int quad = lane >> 4, l15 = lane & 15;
    const int r = tid >> 2, c = (tid & 3) << 3;      // stage 64 rows x 32 halves, 16B/thread
    const int t = blockIdx.x;
    const int row0 = (t >> 2) * 64, col0 = (t & 3) * 64;
    floatx4 acc[2][2] = {};

    for (int k0 = 0; k0 < F_IN; k0 += 32) {
        *(half8*)&As_hi[r * LDSTR + c] = *(const half8*)(A_hi + (size_t)(row0 + r) * F_IN + k0 + c);
        *(half8*)&As_lo[r * LDSTR + c] = *(const half8*)(A_lo + (size_t)(row0 + r) * F_IN + k0 + c);
        *(half8*)&Bs_hi[r * LDSTR + c] = *(const half8*)(Bt_hi + (size_t)(col0 + r) * F_IN + k0 + c);
        *(half8*)&Bs_lo[r * LDSTR + c] = *(const half8*)(Bt_lo + (size_t)(col0 + r) * F_IN + k0 + c);
        __syncthreads();
        half8 a_hi[2], a_lo[2], b_hi[2], b_lo[2];
        #pragma unroll
        for (int mi = 0; mi < 2; ++mi) {
            int mr = wm + mi * 16 + l15;             // A[m=lane&15][k=quad*8+j]
            a_hi[mi] = *(half8*)&As_hi[mr * LDSTR + quad * 8];
            a_lo[mi] = *(half8*)&As_lo[mr * LDSTR + quad * 8];
        }
        #pragma unroll
        for (int ni = 0; ni < 2; ++ni) {
            int nr = wn + ni * 16 + l15;             // B[k][n] from transposed tile
            b_hi[ni] = *(half8*)&Bs_hi[nr * LDSTR + quad * 8];
            b_lo[ni] = *(half8*)&Bs_lo[nr * LDSTR + quad * 8];
        }
        #pragma unroll
        for (int mi = 0; mi < 2; ++mi)
            #pragma unroll
            for (int ni = 0; ni < 2; ++ni) {
                acc[mi][ni] = __builtin_amdgcn_mfma_f32_16x16x32_f16(a_hi[mi], b_hi[ni], acc[mi][ni], 0, 0, 0);
                acc[mi][ni] = __builtin_amdgcn_mfma_f32_16x16x32_f16(a_hi[mi], b_lo[ni], acc[mi][ni], 0, 0, 0);
                acc[mi][ni] = __builtin_amdgcn_mfma_f32_16x16x32_f16(a_lo[mi], b_hi[ni], acc[mi][ni], 0, 0, 0);
            }
        __syncthreads();
    }
    // epilogue: C/D layout col=lane&15, row=quad*4+reg
    #pragma unroll
    for (int mi = 0; mi < 2; ++mi)
        #pragma unroll
        for (int ni = 0; ni < 2; ++ni) {
            int colb = col0 + wn + ni * 16 + l15;
            float bias = b1[colb];
            #pragma unroll
            for (int reg = 0; reg < 4; ++reg) {
                int rowb = row0 + wm + mi * 16 + quad * 4 + reg;
                if (rowb < N_NODES) h0[(size_t)rowb * HID + colb] = acc[mi][ni][reg] + bias;
            }
        }
}

// ---- k_agg1: u0 = relu(agg(h0)) @ W2 + b2  (one wave/node, unroll 8, 4 accumulators) ----

__global__ __launch_bounds__(256) void k_agg1(const float* __restrict__ h0,
                                              const int* __restrict__ csr,
                                              const float* __restrict__ wcsr,
                                              const int* __restrict__ count,
                                              const float* __restrict__ W2,
                                              const float* __restrict__ b2,
                                              float* __restrict__ u0) {
    int n = blockIdx.x * 4 + (threadIdx.x >> 6);
    int lane = threadIdx.x & 63;
    if (n >= N_NODES) return;
    int deg = count[n];
    const int*   row  = csr  + (size_t)n * PAD_DEG;
    const float* wrow = wcsr + (size_t)n * PAD_DEG;
    int off = lane << 2;
    float4 acc0 = {0,0,0,0}, acc1 = {0,0,0,0}, acc2 = {0,0,0,0}, acc3 = {0,0,0,0};
    int j = 0;
    for (; j + 8 <= deg; j += 8) {
        int s0 = row[j+0], s1 = row[j+1], s2 = row[j+2], s3 = row[j+3];
        int s4 = row[j+4], s5 = row[j+5], s6 = row[j+6], s7 = row[j+7];
        float w0 = wrow[j+0], w1 = wrow[j+1], w2 = wrow[j+2], w3 = wrow[j+3];
        float w4 = wrow[j+4], w5 = wrow[j+5], w6 = wrow[j+6], w7 = wrow[j+7];
        float4 v0 = *(const float4*)(h0 + (size_t)s0 * HID + off);
        float4 v1 = *(const float4*)(h0 + (size_t)s1 * HID + off);
        float4 v2 = *(const float4*)(h0 + (size_t)s2 * HID + off);
        float4 v3 = *(const float4*)(h0 + (size_t)s3 * HID + off);
        float4 v4 = *(const float4*)(h0 + (size_t)s4 * HID + off);
        float4 v5 = *(const float4*)(h0 + (size_t)s5 * HID + off);
        float4 v6 = *(const float4*)(h0 + (size_t)s6 * HID + off);
        float4 v7 = *(const float4*)(h0 + (size_t)s7 * HID + off);
        fma4(acc0, w0, v0); fma4(acc1, w1, v1); fma4(acc2, w2, v2); fma4(acc3, w3, v3);
        fma4(acc0, w4, v4); fma4(acc1, w5, v5); fma4(acc2, w6, v6); fma4(acc3, w7, v7);
    }
    for (; j < deg; ++j) {
        float4 v = *(const float4*)(h0 + (size_t)row[j] * HID + off);
        fma4(acc0, wrow[j], v);
    }
    acc0.x += acc1.x + acc2.x + acc3.x;
    acc0.y += acc1.y + acc2.y + acc3.y;
    acc0.z += acc1.z + acc2.z + acc3.z;
    acc0.w += acc1.w + acc2.w + acc3.w;
    acc0.x = fmaxf(acc0.x, 0.f); acc0.y = fmaxf(acc0.y, 0.f);
    acc0.z = fmaxf(acc0.z, 0.f); acc0.w = fmaxf(acc0.w, 0.f);
    float4 wa = *(const float4*)(W2 + (lane << 3));
    float4 wb = *(const float4*)(W2 + (lane << 3) + 4);
    float p0 = acc0.x * wa.x + acc0.y * wa.z + acc0.z * wb.x + acc0.w * wb.z;
    float p1 = acc0.x * wa.y + acc0.y * wa.w + acc0.z * wb.y + acc0.w * wb.w;
    #pragma unroll
    for (int o = 32; o > 0; o >>= 1) {
        p0 += __shfl_down(p0, o);
        p1 += __shfl_down(p1, o);
    }
    if (lane == 0) {
        u0[2 * n]     = p0 + b2[0];
        u0[2 * n + 1] = p1 + b2[1];
    }
}

// ---- k_agg2: second aggregation + Lorentz->Poincare pointwise ----

__global__ __launch_bounds__(256) void k_agg2(const float* __restrict__ u0,
                                              const int* __restrict__ csr,
                                              const float* __restrict__ wcsr,
                                              const int* __restrict__ count,
                                              const float* __restrict__ scale,
                                              float* __restrict__ out) {
    int n = blockIdx.x * 4 + (threadIdx.x >> 6);
    int lane = threadIdx.x & 63;
    if (n >= N_NODES) return;
    int deg = count[n];
    const int*   row  = csr  + (size_t)n * PAD_DEG;
    const float* wrow = wcsr + (size_t)n * PAD_DEG;
    float a0 = 0.f, a1 = 0.f;
    for (int j = lane; j < deg; j += 64) {
        float wq = wrow[j];
        float2 uv = *(const float2*)(u0 + 2 * (size_t)row[j]);
        a0 += wq * uv.x;
        a1 += wq * uv.y;
    }
    #pragma unroll
    for (int o = 32; o > 0; o >>= 1) {
        a0 += __shfl_down(a0, o);
        a1 += __shfl_down(a1, o);
    }
    if (lane == 0) {
        float un = fmaxf(sqrtf(a0 * a0 + a1 * a1), 1e-15f);
        float t = tanhf(0.5f * un) / un;   // sinh/(1+cosh)==tanh(x/2), overflow-proof
        float p0 = a0 * t, p1 = a1 * t;
        float pn = fmaxf(sqrtf(p0 * p0 + p1 * p1), 1e-12f);
        float s = fminf(fmaxf(scale[0], 0.666f), 0.999f);
        p0 = p0 / pn * s; p1 = p1 / pn * s;
        float nn = fmaxf(sqrtf(p0 * p0 + p1 * p1), 1e-15f);
        if (nn > 1.0f) { p0 = p0 / nn; p1 = p1 / nn; }   // (1-1e-15)==1.0f in fp32
        out[2 * n]     = p0;
        out[2 * n + 1] = p1;
    }
}

// ---------------- launch ----------------

extern "C" void kernel_launch(void* const* d_in, const int* in_sizes, int n_in,
                              void* d_out, int out_size, void* d_ws, size_t ws_size,
                              hipStream_t stream) {
    const float* feature = (const float*)d_in[0];
    const int*   ei      = (const int*)d_in[1];
    const float* W1      = (const float*)d_in[2];
    const float* b1      = (const float*)d_in[3];
    const float* W2      = (const float*)d_in[4];
    const float* b2      = (const float*)d_in[5];
    const float* scale   = (const float*)d_in[6];
    float* out = (float*)d_out;

    // workspace layout (byte offsets, all 16B-aligned)
    char* W = (char*)d_ws;
    int*      count = (int*)W;                    // 10240 ints
    int*      csr   = (int*)(W + 40960);          // 800000 ints
    float*    wcsr  = (float*)(W + 3240960);      // 800000 floats
    float*    h0    = (float*)(W + 6440960);      // 10000*256 fp32
    float*    u0    = (float*)(W + 16680960);     // 20000 floats
    _Float16* Bt_hi = (_Float16*)(W + 16760960);  // 256*512 halves
    _Float16* Bt_lo = (_Float16*)(W + 17023104);  // 256*512 halves
    _Float16* A_hi  = (_Float16*)(W + 17285248);  // 10048*512 halves (10.3 MB)
    _Float16* A_lo  = (_Float16*)(W + 27574400);  // 10048*512 halves, ends 37863552 (~37.9 MB)

    (void)hipMemsetAsync(count, 0, 10240 * sizeof(int), stream);

    k_build<<<dim3((A_CHUNKS + 255) / 256), dim3(256), 0, stream>>>(
        ei, feature, W1, count, csr, A_hi, A_lo, Bt_hi, Bt_lo);
    k_prep<<<dim3((N_NODES * PAD_DEG + 255) / 256), dim3(256), 0, stream>>>(csr, count, wcsr);
    k_gemm<<<dim3(N_TILES), dim3(256), 0, stream>>>(A_hi, A_lo, Bt_hi, Bt_lo, b1, h0);
    k_agg1<<<dim3((N_NODES + 3) / 4), dim3(256), 0, stream>>>(h0, csr, wcsr, count, W2, b2, u0);
    k_agg2<<<dim3((N_NODES + 3) / 4), dim3(256), 0, stream>>>(u0, csr, wcsr, count, scale, out);
}

// Round 8
// 158.867 us; speedup vs baseline: 4.2451x; 1.0616x over previous
//
#include <hip/hip_runtime.h>
#include <math.h>

#define N_NODES 10000
#define N_EDGES 320000
#define F_IN 512
#define HID 256
#define PAD_DEG 80    // max in-degree ~60 (Poisson(32) over 10k nodes); 80 is +8.5 sigma
#define LDSTR 40      // LDS row stride in halves (32 + 8 pad, keeps 16B alignment)
#define N_TILES (157 * 4)     // 157 row-tiles x 4 col-tiles of 64x64

typedef _Float16 half8 __attribute__((ext_vector_type(8)));
typedef float floatx4 __attribute__((ext_vector_type(4)));

__device__ __forceinline__ void fma4(float4& acc, float s, const float4& v) {
    acc.x += s * v.x; acc.y += s * v.y; acc.z += s * v.z; acc.w += s * v.w;
}

// ---- k_build: padded-CSR histogram+fill  +  W1 split/transpose (independent work) ----

__global__ void k_build(const int* __restrict__ ei, const float* __restrict__ W1,
                        int* __restrict__ count, int* __restrict__ csr,
                        _Float16* __restrict__ Bt_hi, _Float16* __restrict__ Bt_lo) {
    int i = blockIdx.x * blockDim.x + threadIdx.x;
    if (i < F_IN * HID) {                     // W1 [512][256] -> [256][512] hi/lo split
        int k = i >> 8, n = i & 255;
        float v = W1[i];
        _Float16 hi = (_Float16)v;
        Bt_hi[n * F_IN + k] = hi;
        Bt_lo[n * F_IN + k] = (_Float16)(v - (float)hi);
    }
    if (i < N_EDGES) {                        // padded-CSR build
        int src = ei[i];
        int dst = ei[N_EDGES + i];
        int pos = atomicAdd(&count[dst], 1);  // final value = in-degree
        csr[dst * PAD_DEG + pos] = src;
    }
}

// ---- k_gemm: h0 = feature @ W1 + b1 via 3-term fp16-split MFMA (A converted on the fly) ----

__global__ __launch_bounds__(256) void k_gemm(const float* __restrict__ A,
                                              const _Float16* __restrict__ Bt_hi,
                                              const _Float16* __restrict__ Bt_lo,
                                              const float* __restrict__ b1,
                                              float* __restrict__ h0) {
    __shared__ _Float16 As_hi[64 * LDSTR], As_lo[64 * LDSTR];
    __shared__ _Float16 Bs_hi[64 * LDSTR], Bs_lo[64 * LDSTR];
    const int tid = threadIdx.x;
    const int lane = tid & 63, w = tid >> 6;
    const int wm = (w >> 1) * 32, wn = (w & 1) * 32;
    const int quad = lane >> 4, l15 = lane & 15;
    const int r = tid >> 2, c = (tid & 3) << 3;      // stage 64 rows x 32 halves
    const int t = blockIdx.x;
    const int row0 = (t >> 2) * 64, col0 = (t & 3) * 64;
    floatx4 acc[2][2] = {};

    for (int k0 = 0; k0 < F_IN; k0 += 32) {
        float av[8];
        int arow = row0 + r;
        if (arow < N_NODES) {
            float4 v0 = *(const float4*)(A + (size_t)arow * F_IN + k0 + c);
            float4 v1 = *(const float4*)(A + (size_t)arow * F_IN + k0 + c + 4);
            av[0] = v0.x; av[1] = v0.y; av[2] = v0.z; av[3] = v0.w;
            av[4] = v1.x; av[5] = v1.y; av[6] = v1.z; av[7] = v1.w;
        } else {
            #pragma unroll
            for (int i = 0; i < 8; ++i) av[i] = 0.f;
        }
        half8 hhi, hlo;
        #pragma unroll
        for (int i = 0; i < 8; ++i) {
            _Float16 h = (_Float16)av[i];
            hhi[i] = h;
            hlo[i] = (_Float16)(av[i] - (float)h);
        }
        *(half8*)&As_hi[r * LDSTR + c] = hhi;
        *(half8*)&As_lo[r * LDSTR + c] = hlo;
        *(half8*)&Bs_hi[r * LDSTR + c] = *(const half8*)(Bt_hi + (size_t)(col0 + r) * F_IN + k0 + c);
        *(half8*)&Bs_lo[r * LDSTR + c] = *(const half8*)(Bt_lo + (size_t)(col0 + r) * F_IN + k0 + c);
        __syncthreads();
        half8 a_hi[2], a_lo[2], b_hi[2], b_lo[2];
        #pragma unroll
        for (int mi = 0; mi < 2; ++mi) {
            int mr = wm + mi * 16 + l15;             // A[m=lane&15][k=quad*8+j]
            a_hi[mi] = *(half8*)&As_hi[mr * LDSTR + quad * 8];
            a_lo[mi] = *(half8*)&As_lo[mr * LDSTR + quad * 8];
        }
        #pragma unroll
        for (int ni = 0; ni < 2; ++ni) {
            int nr = wn + ni * 16 + l15;             // B[k][n] from transposed tile
            b_hi[ni] = *(half8*)&Bs_hi[nr * LDSTR + quad * 8];
            b_lo[ni] = *(half8*)&Bs_lo[nr * LDSTR + quad * 8];
        }
        #pragma unroll
        for (int mi = 0; mi < 2; ++mi)
            #pragma unroll
            for (int ni = 0; ni < 2; ++ni) {
                acc[mi][ni] = __builtin_amdgcn_mfma_f32_16x16x32_f16(a_hi[mi], b_hi[ni], acc[mi][ni], 0, 0, 0);
                acc[mi][ni] = __builtin_amdgcn_mfma_f32_16x16x32_f16(a_hi[mi], b_lo[ni], acc[mi][ni], 0, 0, 0);
                acc[mi][ni] = __builtin_amdgcn_mfma_f32_16x16x32_f16(a_lo[mi], b_hi[ni], acc[mi][ni], 0, 0, 0);
            }
        __syncthreads();
    }
    // epilogue: C/D layout col=lane&15, row=quad*4+reg
    #pragma unroll
    for (int mi = 0; mi < 2; ++mi)
        #pragma unroll
        for (int ni = 0; ni < 2; ++ni) {
            int colb = col0 + wn + ni * 16 + l15;
            float bias = b1[colb];
            #pragma unroll
            for (int reg = 0; reg < 4; ++reg) {
                int rowb = row0 + wm + mi * 16 + quad * 4 + reg;
                if (rowb < N_NODES) h0[(size_t)rowb * HID + colb] = acc[mi][ni][reg] + bias;
            }
        }
}

// ---- k_agg1: u0 = relu(agg(h0)) @ W2 + b2 ----
// one wave/node, unroll 8, 4 accumulators; edge weights computed inline from hot count[]

__global__ __launch_bounds__(256) void k_agg1(const float* __restrict__ h0,
                                              const int* __restrict__ csr,
                                              const int* __restrict__ count,
                                              const float* __restrict__ W2,
                                              const float* __restrict__ b2,
                                              float* __restrict__ u0) {
    int n = blockIdx.x * 4 + (threadIdx.x >> 6);
    int lane = threadIdx.x & 63;
    if (n >= N_NODES) return;
    int deg = count[n];
    float degd = (float)(deg > 0 ? deg : 1);
    const int* row = csr + (size_t)n * PAD_DEG;
    int off = lane << 2;
    float4 acc0 = {0,0,0,0}, acc1 = {0,0,0,0}, acc2 = {0,0,0,0}, acc3 = {0,0,0,0};
    int j = 0;
    for (; j + 8 <= deg; j += 8) {
        // wave-uniform metadata (broadcast); 8 independent tiny gathers into hot count[]
        int s0 = row[j+0], s1 = row[j+1], s2 = row[j+2], s3 = row[j+3];
        int s4 = row[j+4], s5 = row[j+5], s6 = row[j+6], s7 = row[j+7];
        int c0 = count[s0], c1 = count[s1], c2 = count[s2], c3 = count[s3];
        int c4 = count[s4], c5 = count[s5], c6 = count[s6], c7 = count[s7];
        float4 v0 = *(const float4*)(h0 + (size_t)s0 * HID + off);
        float4 v1 = *(const float4*)(h0 + (size_t)s1 * HID + off);
        float4 v2 = *(const float4*)(h0 + (size_t)s2 * HID + off);
        float4 v3 = *(const float4*)(h0 + (size_t)s3 * HID + off);
        float4 v4 = *(const float4*)(h0 + (size_t)s4 * HID + off);
        float4 v5 = *(const float4*)(h0 + (size_t)s5 * HID + off);
        float4 v6 = *(const float4*)(h0 + (size_t)s6 * HID + off);
        float4 v7 = *(const float4*)(h0 + (size_t)s7 * HID + off);
        fma4(acc0, rsqrtf((float)(c0 > 0 ? c0 : 1) * degd), v0);
        fma4(acc1, rsqrtf((float)(c1 > 0 ? c1 : 1) * degd), v1);
        fma4(acc2, rsqrtf((float)(c2 > 0 ? c2 : 1) * degd), v2);
        fma4(acc3, rsqrtf((float)(c3 > 0 ? c3 : 1) * degd), v3);
        fma4(acc0, rsqrtf((float)(c4 > 0 ? c4 : 1) * degd), v4);
        fma4(acc1, rsqrtf((float)(c5 > 0 ? c5 : 1) * degd), v5);
        fma4(acc2, rsqrtf((float)(c6 > 0 ? c6 : 1) * degd), v6);
        fma4(acc3, rsqrtf((float)(c7 > 0 ? c7 : 1) * degd), v7);
    }
    for (; j < deg; ++j) {
        int s = row[j];
        int cs = count[s];
        float4 v = *(const float4*)(h0 + (size_t)s * HID + off);
        fma4(acc0, rsqrtf((float)(cs > 0 ? cs : 1) * degd), v);
    }
    acc0.x += acc1.x + acc2.x + acc3.x;
    acc0.y += acc1.y + acc2.y + acc3.y;
    acc0.z += acc1.z + acc2.z + acc3.z;
    acc0.w += acc1.w + acc2.w + acc3.w;
    acc0.x = fmaxf(acc0.x, 0.f); acc0.y = fmaxf(acc0.y, 0.f);
    acc0.z = fmaxf(acc0.z, 0.f); acc0.w = fmaxf(acc0.w, 0.f);
    float4 wa = *(const float4*)(W2 + (lane << 3));
    float4 wb = *(const float4*)(W2 + (lane << 3) + 4);
    float p0 = acc0.x * wa.x + acc0.y * wa.z + acc0.z * wb.x + acc0.w * wb.z;
    float p1 = acc0.x * wa.y + acc0.y * wa.w + acc0.z * wb.y + acc0.w * wb.w;
    #pragma unroll
    for (int o = 32; o > 0; o >>= 1) {
        p0 += __shfl_down(p0, o);
        p1 += __shfl_down(p1, o);
    }
    if (lane == 0) {
        u0[2 * n]     = p0 + b2[0];
        u0[2 * n + 1] = p1 + b2[1];
    }
}

// ---- k_agg2: second aggregation + Lorentz->Poincare pointwise (weights inline) ----

__global__ __launch_bounds__(256) void k_agg2(const float* __restrict__ u0,
                                              const int* __restrict__ csr,
                                              const int* __restrict__ count,
                                              const float* __restrict__ scale,
                                              float* __restrict__ out) {
    int n = blockIdx.x * 4 + (threadIdx.x >> 6);
    int lane = threadIdx.x & 63;
    if (n >= N_NODES) return;
    int deg = count[n];
    float degd = (float)(deg > 0 ? deg : 1);
    const int* row = csr + (size_t)n * PAD_DEG;
    float a0 = 0.f, a1 = 0.f;
    for (int j = lane; j < deg; j += 64) {
        int s = row[j];
        int cs = count[s];
        float wq = rsqrtf((float)(cs > 0 ? cs : 1) * degd);
        float2 uv = *(const float2*)(u0 + 2 * (size_t)s);
        a0 += wq * uv.x;
        a1 += wq * uv.y;
    }
    #pragma unroll
    for (int o = 32; o > 0; o >>= 1) {
        a0 += __shfl_down(a0, o);
        a1 += __shfl_down(a1, o);
    }
    if (lane == 0) {
        float un = fmaxf(sqrtf(a0 * a0 + a1 * a1), 1e-15f);
        float t = tanhf(0.5f * un) / un;   // sinh/(1+cosh)==tanh(x/2), overflow-proof
        float p0 = a0 * t, p1 = a1 * t;
        float pn = fmaxf(sqrtf(p0 * p0 + p1 * p1), 1e-12f);
        float s = fminf(fmaxf(scale[0], 0.666f), 0.999f);
        p0 = p0 / pn * s; p1 = p1 / pn * s;
        float nn = fmaxf(sqrtf(p0 * p0 + p1 * p1), 1e-15f);
        if (nn > 1.0f) { p0 = p0 / nn; p1 = p1 / nn; }   // (1-1e-15)==1.0f in fp32
        out[2 * n]     = p0;
        out[2 * n + 1] = p1;
    }
}

// ---------------- launch ----------------

extern "C" void kernel_launch(void* const* d_in, const int* in_sizes, int n_in,
                              void* d_out, int out_size, void* d_ws, size_t ws_size,
                              hipStream_t stream) {
    const float* feature = (const float*)d_in[0];
    const int*   ei      = (const int*)d_in[1];
    const float* W1      = (const float*)d_in[2];
    const float* b1      = (const float*)d_in[3];
    const float* W2      = (const float*)d_in[4];
    const float* b2      = (const float*)d_in[5];
    const float* scale   = (const float*)d_in[6];
    float* out = (float*)d_out;

    // workspace layout (byte offsets, all 16B-aligned)
    char* W = (char*)d_ws;
    int*      count = (int*)W;                    // 10240 ints
    int*      csr   = (int*)(W + 40960);          // 800000 ints
    float*    h0    = (float*)(W + 3240960);      // 10000*256 fp32
    float*    u0    = (float*)(W + 13480960);     // 20000 floats
    _Float16* Bt_hi = (_Float16*)(W + 13560960);  // 256*512 halves
    _Float16* Bt_lo = (_Float16*)(W + 13823104);  // 256*512 halves  (~14.1 MB total)

    (void)hipMemsetAsync(count, 0, 10240 * sizeof(int), stream);

    k_build<<<dim3((N_EDGES + 255) / 256), dim3(256), 0, stream>>>(
        ei, W1, count, csr, Bt_hi, Bt_lo);
    k_gemm<<<dim3(N_TILES), dim3(256), 0, stream>>>(feature, Bt_hi, Bt_lo, b1, h0);
    k_agg1<<<dim3((N_NODES + 3) / 4), dim3(256), 0, stream>>>(h0, csr, count, W2, b2, u0);
    k_agg2<<<dim3((N_NODES + 3) / 4), dim3(256), 0, stream>>>(u0, csr, count, scale, out);
}